// Round 13
// baseline (324.481 us; speedup 1.0000x reference)
//
#include <hip/hip_runtime.h>
#include <hip/hip_fp16.h>
#include <stdint.h>

typedef unsigned int u32;
typedef unsigned long long u64;
typedef unsigned short ushort_t;

// Problem constants
#define B_ 8
#define C_ 256
#define L_ 2048
#define K_ 8192
#define M_ 16384   // B_*L_

// ---- workspace layout (bytes) ----  (WS_NEED = 25460992, proven to fit)
#define WS_KEYS   0            // u64[16384] -> 131072
#define WS_CNT    131072       // u32
#define WS_MAXCS  131076       // u32 (float bits, positive -> int cmp ok)
#define WS_LOSS   131080       // f32
#define WS_XSQ    131328       // f32[16384] -> 196864
#define WS_CSQ    196864       // f32[8192]  -> 229632
#define WS_GMAX   229632       // u32[16384] ordered-float per-row max -> 295168
#define WS_LIST   295168       // u32[1M]    -> 4489472
#define WS_LMAX   4489472      // fp16 lmaxt[256][16384] -> 12878080 (TRANSPOSED)
#define WS_XTH    12878080     // bf16[16384*256] -> 21266688
#define WS_CBF    21266688     // bf16 fragment-major codebook (4MB) -> 25460992
#define LIST_CAP  1048576u

typedef __attribute__((ext_vector_type(8))) short s8v;   // 8 x bf16 (4 VGPR)
typedef __attribute__((ext_vector_type(4))) float f4v;

__device__ __forceinline__ ushort_t f2bf(float f) {
  u32 u = __float_as_uint(f);
  u32 r = (u + 0x7FFFu + ((u >> 16) & 1u)) >> 16;   // RN-even
  return (ushort_t)r;
}

// monotone float->u32 transform (works for negatives); inverse in vq_thr
__device__ __forceinline__ u32 ordbits(float f) {
  u32 u = __float_as_uint(f);
  return u ^ (((u32)((int)u >> 31)) | 0x80000000u);
}

// ---------------- prep kernels ----------------

// transpose x (B,C,L) -> xt fp32 (M,C) [into emb out region] + bf16 (M,C) [ws]
__global__ void __launch_bounds__(256)
vq_transpose(const float* __restrict__ x, float* __restrict__ xtf,
             ushort_t* __restrict__ xth) {
  __shared__ float t[64][65];
  int tid = threadIdx.x;
  int b  = blockIdx.x >> 7;
  int cc = (blockIdx.x >> 5) & 3;
  int lc = blockIdx.x & 31;
#pragma unroll
  for (int j = 0; j < 4; ++j) {
    int c  = (tid >> 4) + j * 16;
    int lq = tid & 15;
    float4 v = *(const float4*)&x[((size_t)(b * C_ + cc * 64 + c)) * L_ + lc * 64 + lq * 4];
    t[c][lq * 4 + 0] = v.x; t[c][lq * 4 + 1] = v.y;
    t[c][lq * 4 + 2] = v.z; t[c][lq * 4 + 3] = v.w;
  }
  __syncthreads();
  int l = tid >> 2, qc = tid & 3;
  size_t m = (size_t)b * L_ + lc * 64 + l;
#pragma unroll
  for (int j = 0; j < 4; ++j) {
    int q = qc + j * 4;                    // float4 index 0..15
    float4 v = make_float4(t[q * 4 + 0][l], t[q * 4 + 1][l],
                           t[q * 4 + 2][l], t[q * 4 + 3][l]);
    *(float4*)&xtf[m * C_ + cc * 64 + q * 4] = v;
    ushort4 h;
    h.x = f2bf(v.x); h.y = f2bf(v.y); h.z = f2bf(v.z); h.w = f2bf(v.w);
    *(ushort4*)&xth[m * C_ + cc * 64 + q * 4] = h;
  }
}

// xsq from transposed fp32 rows (coalesced, deterministic order)
__global__ void vq_xsqt(const float* __restrict__ xtf, float* __restrict__ xsq) {
  int t = threadIdx.x;
  int m = blockIdx.x * 16 + (t >> 4);              // 1024 blocks
  int g = t & 15;
  const float* row = xtf + (size_t)m * C_;
  float s = 0.0f;
#pragma unroll
  for (int j = 0; j < 4; ++j) {
    float4 v = *(const float4*)&row[g * 4 + j * 64];
    s += v.x * v.x + v.y * v.y + v.z * v.z + v.w * v.w;
  }
#pragma unroll
  for (int off = 1; off < 16; off <<= 1) s += __shfl_xor(s, off, 64);
  if (g == 0) xsq[m] = s;
}

// codebook: csq + maxcs (summation order byte-identical to rounds 1-12 — it
// feeds the tie-sensitive margin) + FRAGMENT-MAJOR bf16 repack:
// cbf[tile(k>>7)][g16((k&127)>>4)][ks][lane(lk*16+lr)] of 16B, so a wave's
// fragment load in vq_gemm is base + l*16 — one contiguous 1KB burst.
__global__ void vq_cbprep(const float* __restrict__ cb, float* __restrict__ csq,
                          int* __restrict__ maxcs, ushort_t* __restrict__ cbf) {
  int t = threadIdx.x;
  int k = blockIdx.x * 16 + (t >> 4);              // 512 blocks
  int g = t & 15;
  const float* row = cb + (size_t)k * C_;
  float s = 0.0f;
#pragma unroll
  for (int j = 0; j < 4; ++j) {
    float4 v = *(const float4*)&row[g * 4 + j * 64];
    s += v.x * v.x + v.y * v.y + v.z * v.z + v.w * v.w;
  }
#pragma unroll
  for (int off = 1; off < 16; off <<= 1) s += __shfl_xor(s, off, 64);
  if (g == 0) {
    csq[k] = s;
    atomicMax(maxcs, __float_as_int(s));   // positive floats: int cmp == float cmp
  }
  // fragment repack: this thread emits 16B chunks c = g and g+16 of row k.
  const int tile = k >> 7, g16 = (k & 127) >> 4, lr = k & 15;
#pragma unroll
  for (int ci = 0; ci < 2; ++ci) {
    int c = g + ci * 16;                   // chunk 0..31; k-range [c*8, c*8+8)
    int ks = c >> 2, lk = c & 3;
    float4 v0 = *(const float4*)&row[c * 8];
    float4 v1 = *(const float4*)&row[c * 8 + 4];
    s8v h;
    h[0] = (short)f2bf(v0.x); h[1] = (short)f2bf(v0.y);
    h[2] = (short)f2bf(v0.z); h[3] = (short)f2bf(v0.w);
    h[4] = (short)f2bf(v1.x); h[5] = (short)f2bf(v1.y);
    h[6] = (short)f2bf(v1.z); h[7] = (short)f2bf(v1.w);
    *(s8v*)&cbf[(size_t)tile * 32768 + g16 * 4096 + ks * 512 + (lk * 16 + lr) * 8] = h;
  }
}

// ---------------- MFMA GEMM, A PINNED in registers, B fragment-major, NO LDS ----------------
// Round 13: rounds 9-12 all reported VGPR_Count <= 128 while a[] alone needs
// 64-128 regs — the compiler REMATERIALIZED the A fragments every tile
// (16 scattered 16B gathers/lane/tile). Fix: asm-pin each fragment ("+v"
// read-write output) — an asm-produced value cannot be rematerialized, only
// kept. __launch_bounds__(512,2) gives the 256-reg budget it needs
// (a 64 + acc 32 + b 16 + addr ~= 150). Geometry = r11 (proven): 512 thr,
// grid 512 = 128 strips x 4 ns, wave = 32 rows x 64 codes, zero barriers —
// waves drift, coalesced 1KB loads pipeline across tiles.

__global__ void __launch_bounds__(512, 2)
vq_gemm(const ushort_t* __restrict__ xth, const ushort_t* __restrict__ cbf,
        const float* __restrict__ csq, __half* __restrict__ lmaxt,
        u32* __restrict__ gmaxu) {
  const int tid = threadIdx.x;
  const int w = tid >> 6, l = tid & 63;
  const int lr = l & 15, lk = l >> 4;
  const int wr = w >> 1, wc = w & 1;
  const int strip = blockIdx.x >> 2, ns = blockIdx.x & 3;
  const int r0 = strip * 128 + wr * 32;
  const int n0 = ns * 2048;

  // A fragments: a[i][ks] = row (r0+i*16+lr), k = ks*32 + lk*8 .. +7  (64 VGPR)
  s8v a[2][8];
#pragma unroll
  for (int i = 0; i < 2; ++i)
#pragma unroll
    for (int ks = 0; ks < 8; ++ks) {
      a[i][ks] = *(const s8v*)&xth[(size_t)(r0 + i * 16 + lr) * 256 + ks * 32 + lk * 8];
      asm volatile("" : "+v"(a[i][ks]));   // pin: asm-produced => no remat
    }

  float rmaxrun[2] = {-1e30f, -1e30f};

  for (int t = 0; t < 16; ++t) {
    // fragment-major tile base: tile index = ns*16 + t
    const ushort_t* tb = cbf + ((size_t)(ns * 16 + t)) * 32768 + (wc * 4) * 4096 + l * 8;

    f4v acc[2][4];
#pragma unroll
    for (int i = 0; i < 2; ++i)
#pragma unroll
      for (int j = 0; j < 4; ++j) acc[i][j] = (f4v){0.f, 0.f, 0.f, 0.f};

#pragma unroll
    for (int ks = 0; ks < 8; ++ks) {
      s8v b[4];
#pragma unroll
      for (int j = 0; j < 4; ++j)
        b[j] = *(const s8v*)&tb[j * 4096 + ks * 512];   // contiguous 1KB per wave
      // SWAPPED operands: D[code][xrow] — lane holds codes lk*4+r, xrow = lr
#pragma unroll
      for (int i = 0; i < 2; ++i)
#pragma unroll
        for (int j = 0; j < 4; ++j)
          acc[i][j] = __builtin_amdgcn_mfma_f32_16x16x32_bf16(b[j], a[i][ks], acc[i][j], 0, 0, 0);
    }

    // epilogue: v = csq - 2*dot; per-lane max over 8 codes (2 j x 4 reg) of a
    // 32-code block, then 2 shuffles over lk. cbase = this wave's code base.
    const int cbase = n0 + t * 128 + wc * 64;
    float vm[2][2];
#pragma unroll
    for (int jp = 0; jp < 2; ++jp) {
      float4 cqa = *(const float4*)&csq[cbase + jp * 32 + lk * 4];
      float4 cqb = *(const float4*)&csq[cbase + jp * 32 + 16 + lk * 4];
#pragma unroll
      for (int i = 0; i < 2; ++i) {
        f4v A0 = acc[i][2 * jp], A1 = acc[i][2 * jp + 1];
        float m0 = fmaxf(fmaxf(__fmaf_rn(-2.0f, A0[0], cqa.x),
                               __fmaf_rn(-2.0f, A0[1], cqa.y)),
                         fmaxf(__fmaf_rn(-2.0f, A0[2], cqa.z),
                               __fmaf_rn(-2.0f, A0[3], cqa.w)));
        float m1 = fmaxf(fmaxf(__fmaf_rn(-2.0f, A1[0], cqb.x),
                               __fmaf_rn(-2.0f, A1[1], cqb.y)),
                         fmaxf(__fmaf_rn(-2.0f, A1[2], cqb.z),
                               __fmaf_rn(-2.0f, A1[3], cqb.w)));
        float vmx = fmaxf(m0, m1);
        vmx = fmaxf(vmx, __shfl_xor(vmx, 16, 64));
        vmx = fmaxf(vmx, __shfl_xor(vmx, 32, 64));
        vm[i][jp] = vmx;
      }
    }
#pragma unroll
    for (int i = 0; i < 2; ++i)
      rmaxrun[i] = fmaxf(rmaxrun[i], fmaxf(vm[i][0], vm[i][1]));
    if (l < 16) {
      // transposed store: col = ns*64 + t*4 + wc*2 + jp; 16 lanes -> 32B line
      const int colb = ns * 64 + t * 4 + wc * 2;
#pragma unroll
      for (int i = 0; i < 2; ++i)
#pragma unroll
        for (int jp = 0; jp < 2; ++jp)
          lmaxt[(size_t)(colb + jp) * M_ + r0 + i * 16 + l] = __float2half(vm[i][jp]);
    }
  }

  // per-row global max (over this wave's 1024 codes); 8 contenders per row
  if (l < 16) {
#pragma unroll
    for (int i = 0; i < 2; ++i)
      atomicMax(&gmaxu[r0 + i * 16 + l], ordbits(rmaxrun[i]));
  }
}

// threshold + candidate list: gmax precomputed in vq_gemm -> single coalesced
// scan of lmaxt. 512 blocks x 256 thr; block owns 32 rows; thread (mloc=t&31,
// cloc=t>>5) scans 8 columns/pass x 32 passes. Candidates buffered in LDS
// (max 32x256=8192 fits exactly); ONE global atomicAdd per block. List order
// is irrelevant: keys are max-combined downstream.
__global__ void __launch_bounds__(256)
vq_thr(const __half* __restrict__ lmaxt, const float* __restrict__ xsq,
       const int* __restrict__ maxcs, const u32* __restrict__ gmaxu,
       u32* __restrict__ list, u32* __restrict__ cnt) {
  __shared__ float thS[32];
  __shared__ u32 buf[8192];
  __shared__ u32 lcnt, gbase;
  const int t = threadIdx.x;
  const int m0 = blockIdx.x * 32;
  if (t == 0) lcnt = 0;
  if (t < 32) {
    u32 tt = gmaxu[m0 + t];
    u32 u = (tt & 0x80000000u) ? (tt ^ 0x80000000u) : ~tt;   // inverse ordbits
    float g = __uint_as_float(u);
    // rigorous: 2*(bf16 dot err bound 2*2^-7*sqrt(xsq*csq)) + fp16 half-ulp
    thS[t] = g - (0.033f * sqrtf(xsq[m0 + t] * __int_as_float(*maxcs)) + 0.6f);
  }
  __syncthreads();
  const int mloc = t & 31, cloc = t >> 5;
  const float th = thS[mloc];
  for (int p = 0; p < 32; ++p) {
    int c = p * 8 + cloc;
    float v = __half2float(lmaxt[(size_t)c * M_ + m0 + mloc]);
    if (v >= th) {
      u32 i = atomicAdd(&lcnt, 1u);
      buf[i] = ((u32)(m0 + mloc) << 8) | (u32)c;
    }
  }
  __syncthreads();
  if (t == 0) gbase = atomicAdd(cnt, lcnt);
  __syncthreads();
  u32 n = lcnt, b0 = gbase;
  for (u32 i = t; i < n; i += 256)
    if (b0 + i < LIST_CAP) list[b0 + i] = buf[i];
}

// exact fp32 rescore of qualifying 32-code blocks; one wave per entry.
// 8 lanes per code x 8 codes in parallel. Mirrors numpy op order incl. sqrt;
// key packs (dist_bits, ~k) => first-max-wins.
__global__ void __launch_bounds__(256)
vq_rescore(const u32* __restrict__ list, const u32* __restrict__ cnt,
           const float* __restrict__ xtf, const float* __restrict__ cb,
           const float* __restrict__ xsq, const float* __restrict__ csq,
           u64* __restrict__ keys) {
  u32 n = *cnt; if (n > LIST_CAP) n = LIST_CAP;
  const int l = threadIdx.x & 63;
  const int u = l & 7;          // lane within 8-lane group
  const int g = l >> 3;         // group 0..7 (one code each)
  int wid = (blockIdx.x * 256 + threadIdx.x) >> 6;
  int nw = (gridDim.x * 256) >> 6;
  for (u32 e = wid; e < n; e += nw) {
    u32 ent = list[e];
    int m = (int)(ent >> 8), blk = (int)(ent & 255u);
    // preload x row chunks for this lane (elements (i*8+u)*4 .. +3)
    float4 xv[8];
#pragma unroll
    for (int i = 0; i < 8; ++i)
      xv[i] = *(const float4*)&xtf[(size_t)m * C_ + (i * 8 + u) * 4];
    float xq = xsq[m];
    u64 bestkey = 0;
#pragma unroll
    for (int cc = 0; cc < 4; ++cc) {
      int k = blk * 32 + cc * 8 + g;
      const float* crow = &cb[(size_t)k * C_];
      float p = 0.0f;
#pragma unroll
      for (int i = 0; i < 8; ++i) {
        float4 cv = *(const float4*)&crow[(i * 8 + u) * 4];
        p += xv[i].x * cv.x + xv[i].y * cv.y + xv[i].z * cv.z + xv[i].w * cv.w;
      }
#pragma unroll
      for (int off = 1; off < 8; off <<= 1) p += __shfl_xor(p, off, 64);
      if (u == 0) {
        // exact reference op order: (x_sq + c_sq) - 2*dot, clamp, sqrt
        float d2 = __fsub_rn(__fadd_rn(xq, csq[k]), __fmul_rn(2.0f, p));
        float dist = sqrtf(fmaxf(d2, 0.0f));
        u64 key = ((u64)__float_as_uint(dist) << 32) |
                  (u64)(0xFFFFFFFFu - (u32)k);
        if (key > bestkey) bestkey = key;   // max dist, tie -> smaller k
      }
    }
    // cross-group max (leaders hold keys; others hold 0)
#pragma unroll
    for (int off = 8; off < 64; off <<= 1) {
      u64 o = __shfl_xor(bestkey, off, 64);
      if (o > bestkey) bestkey = o;
    }
    if (l == 0) atomicMax(&keys[m], bestkey);
  }
}

// ---------------- outputs ----------------

// emb gather + loss partial + code output
__global__ void __launch_bounds__(256)
vq_gather(const u64* __restrict__ keys, const float* __restrict__ cb,
          const float* __restrict__ x, float* __restrict__ out_code,
          float* __restrict__ emb, float* __restrict__ loss_acc) {
  __shared__ float rows[32 * 260];
  __shared__ int codes_s[32];
  __shared__ float partial[4];
  int t = threadIdx.x;
  int b = blockIdx.x >> 6;
  int l0 = (blockIdx.x & 63) * 32;
  if (t < 32) {
    u64 key = keys[b * L_ + l0 + t];
    int code = (int)(0xFFFFFFFFu - (u32)(key & 0xFFFFFFFFull));
    codes_s[t] = code;
    out_code[b * L_ + l0 + t] = (float)code;
  }
  __syncthreads();
  {
    int r = t >> 3, c4 = t & 7;
    const float* src = cb + (size_t)codes_s[r] * C_;
#pragma unroll
    for (int j = 0; j < 8; ++j) {
      float4 v = *(const float4*)&src[(c4 + 8 * j) * 4];
      *(float4*)&rows[r * 260 + (c4 + 8 * j) * 4] = v;
    }
  }
  __syncthreads();
  float ls = 0.0f;
  int l = t & 31, cg = t >> 5;
#pragma unroll 4
  for (int cs = 0; cs < 32; ++cs) {
    int c = cg * 32 + cs;
    float v = rows[l * 260 + c];
    size_t gi = (size_t)(b * C_ + c) * L_ + l0 + l;
    emb[gi] = v;
    float d = x[gi] - v;
    ls = fmaf(d, d, ls);
  }
#pragma unroll
  for (int off = 1; off < 64; off <<= 1) ls += __shfl_xor(ls, off, 64);
  if ((t & 63) == 0) partial[t >> 6] = ls;
  __syncthreads();
  if (t == 0)
    atomicAdd(loss_acc, partial[0] + partial[1] + partial[2] + partial[3]);
}

__global__ void vq_loss(const float* __restrict__ loss_acc, float* __restrict__ out) {
  out[0] = loss_acc[0] / 4194304.0f;
}

extern "C" void kernel_launch(void* const* d_in, const int* in_sizes, int n_in,
                              void* d_out, int out_size, void* d_ws, size_t ws_size,
                              hipStream_t stream) {
  const float* x  = (const float*)d_in[0];   // (8, 256, 2048)
  const float* cb = (const float*)d_in[1];   // (8192, 256)
  float* out = (float*)d_out;                // [code(16384) | emb(4194304) | loss(1)]
  char* ws = (char*)d_ws;

  u64* keys      = (u64*)(ws + WS_KEYS);
  u32* cnt       = (u32*)(ws + WS_CNT);
  int* maxcs     = (int*)(ws + WS_MAXCS);
  float* loss_a  = (float*)(ws + WS_LOSS);
  float* xsq     = (float*)(ws + WS_XSQ);
  float* csq     = (float*)(ws + WS_CSQ);
  u32* gmaxu     = (u32*)(ws + WS_GMAX);
  u32* list      = (u32*)(ws + WS_LIST);
  __half* lmaxt  = (__half*)(ws + WS_LMAX);
  ushort_t* xth  = (ushort_t*)(ws + WS_XTH);
  ushort_t* cbf  = (ushort_t*)(ws + WS_CBF);
  float* xtf     = out + M_;                 // emb region doubles as fp32 x^T scratch

  hipMemsetAsync(ws, 0, 131084, stream);             // keys + cnt + maxcs + loss
  hipMemsetAsync(ws + WS_GMAX, 0, 65536, stream);    // gmaxu (ordbits min)

  vq_transpose<<<1024, 256, 0, stream>>>(x, xtf, xth);
  vq_cbprep<<<K_ / 16, 256, 0, stream>>>(cb, csq, maxcs, cbf);
  vq_xsqt<<<M_ / 16, 256, 0, stream>>>(xtf, xsq);
  vq_gemm<<<512, 512, 0, stream>>>(xth, cbf, csq, lmaxt, gmaxu);
  vq_thr<<<M_ / 32, 256, 0, stream>>>(lmaxt, xsq, maxcs, gmaxu, list, cnt);
  vq_rescore<<<2048, 256, 0, stream>>>(list, cnt, xtf, cb, xsq, csq, keys);
  vq_gather<<<(B_ * L_) / 32, 256, 0, stream>>>(keys, cb, x, out, out + M_, loss_a);
  vq_loss<<<1, 1, 0, stream>>>(loss_a, out + M_ + (size_t)B_ * C_ * L_);
}

// Round 14
// 262.190 us; speedup vs baseline: 1.2376x; 1.2376x over previous
//
#include <hip/hip_runtime.h>
#include <hip/hip_fp16.h>
#include <stdint.h>

typedef unsigned int u32;
typedef unsigned long long u64;
typedef unsigned short ushort_t;

// Problem constants
#define B_ 8
#define C_ 256
#define L_ 2048
#define K_ 8192
#define M_ 16384   // B_*L_

// ---- workspace layout (bytes) ----  (WS_NEED = 25460992, proven to fit)
#define WS_KEYS   0            // u64[16384] -> 131072
#define WS_CNT    131072       // u32
#define WS_MAXCS  131076       // u32 (float bits, positive -> int cmp ok)
#define WS_LOSS   131080       // f32
#define WS_XSQ    131328       // f32[16384] -> 196864
#define WS_CSQ    196864       // f32[8192]  -> 229632
#define WS_GMAX   229632       // u32[16384] ordered-float per-row max -> 295168
#define WS_LIST   295168       // u32[1M]    -> 4489472
#define WS_LMAX   4489472      // fp16 lmaxt[256][16384] -> 12878080 (TRANSPOSED)
#define WS_XTH    12878080     // bf16 FRAGMENT-MAJOR x (8MB) -> 21266688
#define WS_CBF    21266688     // bf16 fragment-major codebook (4MB) -> 25460992
#define LIST_CAP  1048576u

typedef __attribute__((ext_vector_type(8))) short s8v;   // 8 x bf16 (4 VGPR)
typedef __attribute__((ext_vector_type(4))) float f4v;

__device__ __forceinline__ ushort_t f2bf(float f) {
  u32 u = __float_as_uint(f);
  u32 r = (u + 0x7FFFu + ((u >> 16) & 1u)) >> 16;   // RN-even
  return (ushort_t)r;
}

// monotone float->u32 transform (works for negatives); inverse in vq_thr
__device__ __forceinline__ u32 ordbits(float f) {
  u32 u = __float_as_uint(f);
  return u ^ (((u32)((int)u >> 31)) | 0x80000000u);
}

// ---------------- prep kernels ----------------

// transpose x (B,C,L) -> xtf fp32 (M,C) [into emb out region] +
// xthf bf16 FRAGMENT-MAJOR: xthf[g16m][ks][lane] 16B chunks, where lane
// l = lk*16+lr holds row g16m*16+lr, k = ks*32+lk*8 .. +7 — exactly the
// MFMA A-operand vq_gemm consumes, so every A load is a coalesced 1KB burst
// (round 14: r10-r13 showed scattered 16B fragment gathers are the tax).
__global__ void __launch_bounds__(256)
vq_transpose(const float* __restrict__ x, float* __restrict__ xtf,
             ushort_t* __restrict__ xthf) {
  __shared__ float t[64][65];
  int tid = threadIdx.x;
  int b  = blockIdx.x >> 7;
  int cc = (blockIdx.x >> 5) & 3;
  int lc = blockIdx.x & 31;
#pragma unroll
  for (int j = 0; j < 4; ++j) {
    int c  = (tid >> 4) + j * 16;
    int lq = tid & 15;
    float4 v = *(const float4*)&x[((size_t)(b * C_ + cc * 64 + c)) * L_ + lc * 64 + lq * 4];
    t[c][lq * 4 + 0] = v.x; t[c][lq * 4 + 1] = v.y;
    t[c][lq * 4 + 2] = v.z; t[c][lq * 4 + 3] = v.w;
  }
  __syncthreads();
  // phase 2a: fp32 row-major xtf (feeds exact rescore)
  {
    int l = tid >> 2, qc = tid & 3;
    size_t m = (size_t)b * L_ + lc * 64 + l;
#pragma unroll
    for (int j = 0; j < 4; ++j) {
      int q = qc + j * 4;                  // float4 index 0..15
      float4 v = make_float4(t[q * 4 + 0][l], t[q * 4 + 1][l],
                             t[q * 4 + 2][l], t[q * 4 + 3][l]);
      *(float4*)&xtf[m * C_ + cc * 64 + q * 4] = v;
    }
  }
  // phase 2b: bf16 fragment-major xthf — 8 fragments of 64 lanes per block
  const int g16b = b * 128 + lc * 4;
#pragma unroll
  for (int jj = 0; jj < 2; ++jj) {
    int f = (tid >> 6) + 4 * jj;           // fragment 0..7
    int lane = tid & 63;
    int g16loc = f & 3, ksl = f >> 2;      // row group, local ks
    int lk = lane >> 4, lr = lane & 15;
    int lrow = g16loc * 16 + lr;
    int kl = ksl * 32 + lk * 8;            // k within this cc block
    s8v h;
#pragma unroll
    for (int e = 0; e < 8; ++e) h[e] = (short)f2bf(t[kl + e][lrow]);
    *(s8v*)&xthf[((size_t)(g16b + g16loc) * 8 + (cc * 2 + ksl)) * 512 + lane * 8] = h;
  }
}

// xsq from transposed fp32 rows (coalesced, deterministic order)
__global__ void vq_xsqt(const float* __restrict__ xtf, float* __restrict__ xsq) {
  int t = threadIdx.x;
  int m = blockIdx.x * 16 + (t >> 4);              // 1024 blocks
  int g = t & 15;
  const float* row = xtf + (size_t)m * C_;
  float s = 0.0f;
#pragma unroll
  for (int j = 0; j < 4; ++j) {
    float4 v = *(const float4*)&row[g * 4 + j * 64];
    s += v.x * v.x + v.y * v.y + v.z * v.z + v.w * v.w;
  }
#pragma unroll
  for (int off = 1; off < 16; off <<= 1) s += __shfl_xor(s, off, 64);
  if (g == 0) xsq[m] = s;
}

// codebook: csq + maxcs (summation order byte-identical to rounds 1-13 — it
// feeds the tie-sensitive margin) + FRAGMENT-MAJOR bf16 repack:
// cbf[tile(k>>7)][g16((k&127)>>4)][ks][lane(lk*16+lr)] of 16B.
__global__ void vq_cbprep(const float* __restrict__ cb, float* __restrict__ csq,
                          int* __restrict__ maxcs, ushort_t* __restrict__ cbf) {
  int t = threadIdx.x;
  int k = blockIdx.x * 16 + (t >> 4);              // 512 blocks
  int g = t & 15;
  const float* row = cb + (size_t)k * C_;
  float s = 0.0f;
#pragma unroll
  for (int j = 0; j < 4; ++j) {
    float4 v = *(const float4*)&row[g * 4 + j * 64];
    s += v.x * v.x + v.y * v.y + v.z * v.z + v.w * v.w;
  }
#pragma unroll
  for (int off = 1; off < 16; off <<= 1) s += __shfl_xor(s, off, 64);
  if (g == 0) {
    csq[k] = s;
    atomicMax(maxcs, __float_as_int(s));   // positive floats: int cmp == float cmp
  }
  // fragment repack: this thread emits 16B chunks c = g and g+16 of row k.
  const int tile = k >> 7, g16 = (k & 127) >> 4, lr = k & 15;
#pragma unroll
  for (int ci = 0; ci < 2; ++ci) {
    int c = g + ci * 16;                   // chunk 0..31; k-range [c*8, c*8+8)
    int ks = c >> 2, lk = c & 3;
    float4 v0 = *(const float4*)&row[c * 8];
    float4 v1 = *(const float4*)&row[c * 8 + 4];
    s8v h;
    h[0] = (short)f2bf(v0.x); h[1] = (short)f2bf(v0.y);
    h[2] = (short)f2bf(v0.z); h[3] = (short)f2bf(v0.w);
    h[4] = (short)f2bf(v1.x); h[5] = (short)f2bf(v1.y);
    h[6] = (short)f2bf(v1.z); h[7] = (short)f2bf(v1.w);
    *(s8v*)&cbf[(size_t)tile * 32768 + g16 * 4096 + ks * 512 + (lk * 16 + lr) * 8] = h;
  }
}

// ---------------- MFMA GEMM, A+B both fragment-major coalesced, NO LDS ----------------
// Round 14: r11 geometry (proven best no-LDS: 512 thr, 4 waves/SIMD, grid 512
// = 128 strips x 4 ns, zero barriers) + fragment-major A. Now EVERY memory
// access in the kernel is a coalesced 1KB burst; whether the compiler keeps A
// resident or reloads it per tile, the cost is bounded by L1 bandwidth on an
// L1-resident 16KB slice, not by scattered 64B transactions.

__global__ void __launch_bounds__(512, 4)
vq_gemm(const ushort_t* __restrict__ xthf, const ushort_t* __restrict__ cbf,
        const float* __restrict__ csq, __half* __restrict__ lmaxt,
        u32* __restrict__ gmaxu) {
  const int tid = threadIdx.x;
  const int w = tid >> 6, l = tid & 63;
  const int lr = l & 15, lk = l >> 4;
  const int wr = w >> 1, wc = w & 1;
  const int strip = blockIdx.x >> 2, ns = blockIdx.x & 3;
  const int r0 = strip * 128 + wr * 32;
  const int n0 = ns * 2048;

  // A fragments, coalesced: frag (g16m = strip*8+wr*2+i, ks), my 16B at l*16
  s8v a[2][8];
#pragma unroll
  for (int i = 0; i < 2; ++i)
#pragma unroll
    for (int ks = 0; ks < 8; ++ks)
      a[i][ks] = *(const s8v*)&xthf[((size_t)(strip * 8 + wr * 2 + i) * 8 + ks) * 512 + l * 8];

  float rmaxrun[2] = {-1e30f, -1e30f};

  for (int t = 0; t < 16; ++t) {
    // fragment-major tile base: tile index = ns*16 + t
    const ushort_t* tb = cbf + ((size_t)(ns * 16 + t)) * 32768 + (wc * 4) * 4096 + l * 8;

    f4v acc[2][4];
#pragma unroll
    for (int i = 0; i < 2; ++i)
#pragma unroll
      for (int j = 0; j < 4; ++j) acc[i][j] = (f4v){0.f, 0.f, 0.f, 0.f};

#pragma unroll
    for (int ks = 0; ks < 8; ++ks) {
      s8v b[4];
#pragma unroll
      for (int j = 0; j < 4; ++j)
        b[j] = *(const s8v*)&tb[j * 4096 + ks * 512];   // contiguous 1KB per wave
      // SWAPPED operands: D[code][xrow] — lane holds codes lk*4+r, xrow = lr
#pragma unroll
      for (int i = 0; i < 2; ++i)
#pragma unroll
        for (int j = 0; j < 4; ++j)
          acc[i][j] = __builtin_amdgcn_mfma_f32_16x16x32_bf16(b[j], a[i][ks], acc[i][j], 0, 0, 0);
    }

    // epilogue: v = csq - 2*dot; per-lane max over 8 codes (2 j x 4 reg) of a
    // 32-code block, then 2 shuffles over lk. cbase = this wave's code base.
    const int cbase = n0 + t * 128 + wc * 64;
    float vm[2][2];
#pragma unroll
    for (int jp = 0; jp < 2; ++jp) {
      float4 cqa = *(const float4*)&csq[cbase + jp * 32 + lk * 4];
      float4 cqb = *(const float4*)&csq[cbase + jp * 32 + 16 + lk * 4];
#pragma unroll
      for (int i = 0; i < 2; ++i) {
        f4v A0 = acc[i][2 * jp], A1 = acc[i][2 * jp + 1];
        float m0 = fmaxf(fmaxf(__fmaf_rn(-2.0f, A0[0], cqa.x),
                               __fmaf_rn(-2.0f, A0[1], cqa.y)),
                         fmaxf(__fmaf_rn(-2.0f, A0[2], cqa.z),
                               __fmaf_rn(-2.0f, A0[3], cqa.w)));
        float m1 = fmaxf(fmaxf(__fmaf_rn(-2.0f, A1[0], cqb.x),
                               __fmaf_rn(-2.0f, A1[1], cqb.y)),
                         fmaxf(__fmaf_rn(-2.0f, A1[2], cqb.z),
                               __fmaf_rn(-2.0f, A1[3], cqb.w)));
        float vmx = fmaxf(m0, m1);
        vmx = fmaxf(vmx, __shfl_xor(vmx, 16, 64));
        vmx = fmaxf(vmx, __shfl_xor(vmx, 32, 64));
        vm[i][jp] = vmx;
      }
    }
#pragma unroll
    for (int i = 0; i < 2; ++i)
      rmaxrun[i] = fmaxf(rmaxrun[i], fmaxf(vm[i][0], vm[i][1]));
    if (l < 16) {
      // transposed store: col = ns*64 + t*4 + wc*2 + jp; 16 lanes -> 32B line
      const int colb = ns * 64 + t * 4 + wc * 2;
#pragma unroll
      for (int i = 0; i < 2; ++i)
#pragma unroll
        for (int jp = 0; jp < 2; ++jp)
          lmaxt[(size_t)(colb + jp) * M_ + r0 + i * 16 + l] = __float2half(vm[i][jp]);
    }
  }

  // per-row global max (over this wave's 1024 codes); 8 contenders per row
  if (l < 16) {
#pragma unroll
    for (int i = 0; i < 2; ++i)
      atomicMax(&gmaxu[r0 + i * 16 + l], ordbits(rmaxrun[i]));
  }
}

// threshold + candidate list: gmax precomputed in vq_gemm -> single coalesced
// scan of lmaxt. 512 blocks x 256 thr; block owns 32 rows; thread (mloc=t&31,
// cloc=t>>5) scans 8 columns/pass x 32 passes. Candidates buffered in LDS
// (max 32x256=8192 fits exactly); ONE global atomicAdd per block. List order
// is irrelevant: keys are max-combined downstream.
__global__ void __launch_bounds__(256)
vq_thr(const __half* __restrict__ lmaxt, const float* __restrict__ xsq,
       const int* __restrict__ maxcs, const u32* __restrict__ gmaxu,
       u32* __restrict__ list, u32* __restrict__ cnt) {
  __shared__ float thS[32];
  __shared__ u32 buf[8192];
  __shared__ u32 lcnt, gbase;
  const int t = threadIdx.x;
  const int m0 = blockIdx.x * 32;
  if (t == 0) lcnt = 0;
  if (t < 32) {
    u32 tt = gmaxu[m0 + t];
    u32 u = (tt & 0x80000000u) ? (tt ^ 0x80000000u) : ~tt;   // inverse ordbits
    float g = __uint_as_float(u);
    // rigorous: 2*(bf16 dot err bound 2*2^-7*sqrt(xsq*csq)) + fp16 half-ulp
    thS[t] = g - (0.033f * sqrtf(xsq[m0 + t] * __int_as_float(*maxcs)) + 0.6f);
  }
  __syncthreads();
  const int mloc = t & 31, cloc = t >> 5;
  const float th = thS[mloc];
  for (int p = 0; p < 32; ++p) {
    int c = p * 8 + cloc;
    float v = __half2float(lmaxt[(size_t)c * M_ + m0 + mloc]);
    if (v >= th) {
      u32 i = atomicAdd(&lcnt, 1u);
      buf[i] = ((u32)(m0 + mloc) << 8) | (u32)c;
    }
  }
  __syncthreads();
  if (t == 0) gbase = atomicAdd(cnt, lcnt);
  __syncthreads();
  u32 n = lcnt, b0 = gbase;
  for (u32 i = t; i < n; i += 256)
    if (b0 + i < LIST_CAP) list[b0 + i] = buf[i];
}

// exact fp32 rescore of qualifying 32-code blocks; one wave per entry.
// 8 lanes per code x 8 codes in parallel. Mirrors numpy op order incl. sqrt;
// key packs (dist_bits, ~k) => first-max-wins.
__global__ void __launch_bounds__(256)
vq_rescore(const u32* __restrict__ list, const u32* __restrict__ cnt,
           const float* __restrict__ xtf, const float* __restrict__ cb,
           const float* __restrict__ xsq, const float* __restrict__ csq,
           u64* __restrict__ keys) {
  u32 n = *cnt; if (n > LIST_CAP) n = LIST_CAP;
  const int l = threadIdx.x & 63;
  const int u = l & 7;          // lane within 8-lane group
  const int g = l >> 3;         // group 0..7 (one code each)
  int wid = (blockIdx.x * 256 + threadIdx.x) >> 6;
  int nw = (gridDim.x * 256) >> 6;
  for (u32 e = wid; e < n; e += nw) {
    u32 ent = list[e];
    int m = (int)(ent >> 8), blk = (int)(ent & 255u);
    // preload x row chunks for this lane (elements (i*8+u)*4 .. +3)
    float4 xv[8];
#pragma unroll
    for (int i = 0; i < 8; ++i)
      xv[i] = *(const float4*)&xtf[(size_t)m * C_ + (i * 8 + u) * 4];
    float xq = xsq[m];
    u64 bestkey = 0;
#pragma unroll
    for (int cc = 0; cc < 4; ++cc) {
      int k = blk * 32 + cc * 8 + g;
      const float* crow = &cb[(size_t)k * C_];
      float p = 0.0f;
#pragma unroll
      for (int i = 0; i < 8; ++i) {
        float4 cv = *(const float4*)&crow[(i * 8 + u) * 4];
        p += xv[i].x * cv.x + xv[i].y * cv.y + xv[i].z * cv.z + xv[i].w * cv.w;
      }
#pragma unroll
      for (int off = 1; off < 8; off <<= 1) p += __shfl_xor(p, off, 64);
      if (u == 0) {
        // exact reference op order: (x_sq + c_sq) - 2*dot, clamp, sqrt
        float d2 = __fsub_rn(__fadd_rn(xq, csq[k]), __fmul_rn(2.0f, p));
        float dist = sqrtf(fmaxf(d2, 0.0f));
        u64 key = ((u64)__float_as_uint(dist) << 32) |
                  (u64)(0xFFFFFFFFu - (u32)k);
        if (key > bestkey) bestkey = key;   // max dist, tie -> smaller k
      }
    }
    // cross-group max (leaders hold keys; others hold 0)
#pragma unroll
    for (int off = 8; off < 64; off <<= 1) {
      u64 o = __shfl_xor(bestkey, off, 64);
      if (o > bestkey) bestkey = o;
    }
    if (l == 0) atomicMax(&keys[m], bestkey);
  }
}

// ---------------- outputs ----------------

// emb gather + loss partial + code output
__global__ void __launch_bounds__(256)
vq_gather(const u64* __restrict__ keys, const float* __restrict__ cb,
          const float* __restrict__ x, float* __restrict__ out_code,
          float* __restrict__ emb, float* __restrict__ loss_acc) {
  __shared__ float rows[32 * 260];
  __shared__ int codes_s[32];
  __shared__ float partial[4];
  int t = threadIdx.x;
  int b = blockIdx.x >> 6;
  int l0 = (blockIdx.x & 63) * 32;
  if (t < 32) {
    u64 key = keys[b * L_ + l0 + t];
    int code = (int)(0xFFFFFFFFu - (u32)(key & 0xFFFFFFFFull));
    codes_s[t] = code;
    out_code[b * L_ + l0 + t] = (float)code;
  }
  __syncthreads();
  {
    int r = t >> 3, c4 = t & 7;
    const float* src = cb + (size_t)codes_s[r] * C_;
#pragma unroll
    for (int j = 0; j < 8; ++j) {
      float4 v = *(const float4*)&src[(c4 + 8 * j) * 4];
      *(float4*)&rows[r * 260 + (c4 + 8 * j) * 4] = v;
    }
  }
  __syncthreads();
  float ls = 0.0f;
  int l = t & 31, cg = t >> 5;
#pragma unroll 4
  for (int cs = 0; cs < 32; ++cs) {
    int c = cg * 32 + cs;
    float v = rows[l * 260 + c];
    size_t gi = (size_t)(b * C_ + c) * L_ + l0 + l;
    emb[gi] = v;
    float d = x[gi] - v;
    ls = fmaf(d, d, ls);
  }
#pragma unroll
  for (int off = 1; off < 64; off <<= 1) ls += __shfl_xor(ls, off, 64);
  if ((t & 63) == 0) partial[t >> 6] = ls;
  __syncthreads();
  if (t == 0)
    atomicAdd(loss_acc, partial[0] + partial[1] + partial[2] + partial[3]);
}

__global__ void vq_loss(const float* __restrict__ loss_acc, float* __restrict__ out) {
  out[0] = loss_acc[0] / 4194304.0f;
}

extern "C" void kernel_launch(void* const* d_in, const int* in_sizes, int n_in,
                              void* d_out, int out_size, void* d_ws, size_t ws_size,
                              hipStream_t stream) {
  const float* x  = (const float*)d_in[0];   // (8, 256, 2048)
  const float* cb = (const float*)d_in[1];   // (8192, 256)
  float* out = (float*)d_out;                // [code(16384) | emb(4194304) | loss(1)]
  char* ws = (char*)d_ws;

  u64* keys      = (u64*)(ws + WS_KEYS);
  u32* cnt       = (u32*)(ws + WS_CNT);
  int* maxcs     = (int*)(ws + WS_MAXCS);
  float* loss_a  = (float*)(ws + WS_LOSS);
  float* xsq     = (float*)(ws + WS_XSQ);
  float* csq     = (float*)(ws + WS_CSQ);
  u32* gmaxu     = (u32*)(ws + WS_GMAX);
  u32* list      = (u32*)(ws + WS_LIST);
  __half* lmaxt  = (__half*)(ws + WS_LMAX);
  ushort_t* xthf = (ushort_t*)(ws + WS_XTH);
  ushort_t* cbf  = (ushort_t*)(ws + WS_CBF);
  float* xtf     = out + M_;                 // emb region doubles as fp32 x^T scratch

  hipMemsetAsync(ws, 0, 131084, stream);             // keys + cnt + maxcs + loss
  hipMemsetAsync(ws + WS_GMAX, 0, 65536, stream);    // gmaxu (ordbits min)

  vq_transpose<<<1024, 256, 0, stream>>>(x, xtf, xthf);
  vq_cbprep<<<K_ / 16, 256, 0, stream>>>(cb, csq, maxcs, cbf);
  vq_xsqt<<<M_ / 16, 256, 0, stream>>>(xtf, xsq);
  vq_gemm<<<512, 512, 0, stream>>>(xthf, cbf, csq, lmaxt, gmaxu);
  vq_thr<<<M_ / 32, 256, 0, stream>>>(lmaxt, xsq, maxcs, gmaxu, list, cnt);
  vq_rescore<<<2048, 256, 0, stream>>>(list, cnt, xtf, cb, xsq, csq, keys);
  vq_gather<<<(B_ * L_) / 32, 256, 0, stream>>>(keys, cb, x, out, out + M_, loss_a);
  vq_loss<<<1, 1, 0, stream>>>(loss_a, out + M_ + (size_t)B_ * C_ * L_);
}